// Round 1
// baseline (389.352 us; speedup 1.0000x reference)
//
#include <hip/hip_runtime.h>

// Problem constants
constexpr int Bsz   = 128;
constexpr int IMGC  = 256;
constexpr int PP    = 16;
constexpr int CC    = 3;
constexpr int EE    = 200;   // embed dim
constexpr int NN    = 256;   // num patches
constexpr int NMASK = 192;
constexpr int NVIS  = 64;
constexpr int PE    = 768;   // patch elems = C*P*P
constexpr int M1    = Bsz * NVIS;     // 8192 visible rows
constexpr int M3    = M1 + NMASK;     // 8384 decoder rows
constexpr long IMG_ELEMS = (long)Bsz * CC * IMGC * IMGC; // 25165824

// ---------------------------------------------------------------------------
// GEMM1: visible patch embedding.
// visible[m][e] = sum_p patch(b,n)[p] * w_flat[e][p] + conv_b[e] + pos[n][e]
// m = b*64 + j, n = perm[192+j].  M=8192, K=768, N=200.
// A is gathered from x on the fly (k-tile of 16 == one contiguous 16-float
// pixel row of a patch since K%16 aligns with px).
// ---------------------------------------------------------------------------
__global__ __launch_bounds__(256) void k_gemm1(
    const float* __restrict__ x, const float* __restrict__ wflat,
    const float* __restrict__ convb, const float* __restrict__ pos,
    const int* __restrict__ perm, float* __restrict__ visible)
{
    __shared__ float As[16][68];
    __shared__ float Bs[16][68];
    const int t  = threadIdx.x;
    const int m0 = blockIdx.y * 64;
    const int e0 = blockIdx.x * 64;
    const int tm = t >> 4, tn = t & 15;
    const int lk = t & 15, lrow = t >> 4;

    float acc[4][4] = {};

    // Precompute gather bases for the 4 A-rows this thread loads.
    int abase[4];
    #pragma unroll
    for (int r = 0; r < 4; ++r) {
        int m = m0 + lrow + 16 * r;
        int b = m >> 6, j = m & 63;
        int n = perm[NMASK + j];
        int gy = n >> 4, gx = n & 15;
        abase[r] = ((b * 3) * 256 + gy * 16) * 256 + gx * 16;
    }

    for (int k0 = 0; k0 < PE; k0 += 16) {
        int k  = k0 + lk;
        int c  = k >> 8, py = (k >> 4) & 15, px = k & 15;
        int aoff = c * 65536 + py * 256 + px;
        #pragma unroll
        for (int r = 0; r < 4; ++r)
            As[lk][lrow + 16 * r] = x[abase[r] + aoff];
        #pragma unroll
        for (int r = 0; r < 4; ++r) {
            int ni = lrow + 16 * r;
            int e  = e0 + ni;
            Bs[lk][ni] = (e < EE) ? wflat[e * PE + k] : 0.0f;
        }
        __syncthreads();
        #pragma unroll
        for (int kk = 0; kk < 16; ++kk) {
            const float4 a4 = *(const float4*)(&As[kk][tm * 4]);
            const float4 b4 = *(const float4*)(&Bs[kk][tn * 4]);
            const float av[4] = {a4.x, a4.y, a4.z, a4.w};
            const float bv[4] = {b4.x, b4.y, b4.z, b4.w};
            #pragma unroll
            for (int i = 0; i < 4; ++i)
                #pragma unroll
                for (int j = 0; j < 4; ++j)
                    acc[i][j] = fmaf(av[i], bv[j], acc[i][j]);
        }
        __syncthreads();
    }

    #pragma unroll
    for (int i = 0; i < 4; ++i) {
        int m = m0 + tm * 4 + i;
        int n = perm[NMASK + (m & 63)];
        #pragma unroll
        for (int j = 0; j < 4; ++j) {
            int e = e0 + tn * 4 + j;
            if (e < EE)
                visible[m * EE + e] = acc[i][j] + convb[e] + pos[n * EE + e];
        }
    }
}

// ---------------------------------------------------------------------------
// GEMM2: encoder.  full[m][f] = sum_e visible[m][e]*Wenc[e][f] + benc[f] + pos[n][f]
// M=8192, K=200, N=200.
// ---------------------------------------------------------------------------
__global__ __launch_bounds__(256) void k_gemm2(
    const float* __restrict__ visible, const float* __restrict__ Wenc,
    const float* __restrict__ benc, const float* __restrict__ pos,
    const int* __restrict__ perm, float* __restrict__ full)
{
    __shared__ float As[16][68];
    __shared__ float Bs[16][68];
    const int t  = threadIdx.x;
    const int m0 = blockIdx.y * 64;
    const int e0 = blockIdx.x * 64;
    const int tm = t >> 4, tn = t & 15;
    const int lk = t & 15, lrow = t >> 4;
    const int bn = t & 63, bk = t >> 6;

    float acc[4][4] = {};

    for (int k0 = 0; k0 < EE; k0 += 16) {
        #pragma unroll
        for (int r = 0; r < 4; ++r) {
            int mi = lrow + 16 * r;
            int k  = k0 + lk;
            As[lk][mi] = (k < EE) ? visible[(m0 + mi) * EE + k] : 0.0f;
        }
        #pragma unroll
        for (int r = 0; r < 4; ++r) {
            int kk = bk + 4 * r;
            int k  = k0 + kk;
            int e  = e0 + bn;
            Bs[kk][bn] = (k < EE && e < EE) ? Wenc[k * EE + e] : 0.0f;
        }
        __syncthreads();
        #pragma unroll
        for (int kk = 0; kk < 16; ++kk) {
            const float4 a4 = *(const float4*)(&As[kk][tm * 4]);
            const float4 b4 = *(const float4*)(&Bs[kk][tn * 4]);
            const float av[4] = {a4.x, a4.y, a4.z, a4.w};
            const float bv[4] = {b4.x, b4.y, b4.z, b4.w};
            #pragma unroll
            for (int i = 0; i < 4; ++i)
                #pragma unroll
                for (int j = 0; j < 4; ++j)
                    acc[i][j] = fmaf(av[i], bv[j], acc[i][j]);
        }
        __syncthreads();
    }

    #pragma unroll
    for (int i = 0; i < 4; ++i) {
        int m = m0 + tm * 4 + i;
        int n = perm[NMASK + (m & 63)];
        #pragma unroll
        for (int j = 0; j < 4; ++j) {
            int e = e0 + tn * 4 + j;
            if (e < EE)
                full[m * EE + e] = acc[i][j] + benc[e] + pos[n * EE + e];
        }
    }
}

// ---------------------------------------------------------------------------
// Mask rows: full[M1+m][e] = mask_token[e] + pos[perm[m]][e]   (192 x 200)
// ---------------------------------------------------------------------------
__global__ void k_maskrows(const float* __restrict__ mask_token,
                           const float* __restrict__ pos,
                           const int* __restrict__ perm,
                           float* __restrict__ full)
{
    int idx = blockIdx.x * blockDim.x + threadIdx.x;
    if (idx < NMASK * EE) {
        int m = idx / EE, e = idx % EE;
        int n = perm[m];
        full[(M1 + m) * EE + e] = mask_token[e] + pos[n * EE + e];
    }
}

// ---------------------------------------------------------------------------
// GEMM3: decoder.  dec[m][p] = sum_e full[m][e]*Wdec[e][p] + bdec[p]
// M=8384, K=200, N=768.
// ---------------------------------------------------------------------------
__global__ __launch_bounds__(256) void k_gemm3(
    const float* __restrict__ full, const float* __restrict__ Wdec,
    const float* __restrict__ bdec, float* __restrict__ dec)
{
    __shared__ float As[16][68];
    __shared__ float Bs[16][68];
    const int t  = threadIdx.x;
    const int m0 = blockIdx.y * 64;
    const int e0 = blockIdx.x * 64;
    const int tm = t >> 4, tn = t & 15;
    const int lk = t & 15, lrow = t >> 4;
    const int bn = t & 63, bk = t >> 6;

    float acc[4][4] = {};

    for (int k0 = 0; k0 < EE; k0 += 16) {
        #pragma unroll
        for (int r = 0; r < 4; ++r) {
            int mi = lrow + 16 * r;
            int k  = k0 + lk;
            As[lk][mi] = (k < EE) ? full[(m0 + mi) * EE + k] : 0.0f;
        }
        #pragma unroll
        for (int r = 0; r < 4; ++r) {
            int kk = bk + 4 * r;
            int k  = k0 + kk;
            Bs[kk][bn] = (k < EE) ? Wdec[k * PE + e0 + bn] : 0.0f;
        }
        __syncthreads();
        #pragma unroll
        for (int kk = 0; kk < 16; ++kk) {
            const float4 a4 = *(const float4*)(&As[kk][tm * 4]);
            const float4 b4 = *(const float4*)(&Bs[kk][tn * 4]);
            const float av[4] = {a4.x, a4.y, a4.z, a4.w};
            const float bv[4] = {b4.x, b4.y, b4.z, b4.w};
            #pragma unroll
            for (int i = 0; i < 4; ++i)
                #pragma unroll
                for (int j = 0; j < 4; ++j)
                    acc[i][j] = fmaf(av[i], bv[j], acc[i][j]);
        }
        __syncthreads();
    }

    #pragma unroll
    for (int i = 0; i < 4; ++i) {
        int m = m0 + tm * 4 + i;
        #pragma unroll
        for (int j = 0; j < 4; ++j) {
            int e = e0 + tn * 4 + j;
            dec[(long)m * PE + e] = acc[i][j] + bdec[e];
        }
    }
}

// ---------------------------------------------------------------------------
// Prep: build n -> decoder-row map; emit masked_idx output (as floats).
// ---------------------------------------------------------------------------
__global__ void k_prep(const int* __restrict__ perm, int* __restrict__ row_of,
                       float* __restrict__ out_idx)
{
    int t = threadIdx.x;
    if (t < NN) {
        int n = perm[t];
        row_of[n] = (t < NMASK) ? (M1 + t) : (t - NMASK);
    }
    if (t < NMASK) out_idx[t] = (float)perm[t];
}

// ---------------------------------------------------------------------------
// Fold: scatter dec rows into the output image.  Masked rows (row >= M1) are
// batch-independent and broadcast to all 128 images.
// ---------------------------------------------------------------------------
__global__ __launch_bounds__(192) void k_fold(const float* __restrict__ dec,
                                              const int* __restrict__ row_of,
                                              float* __restrict__ img)
{
    int blk = blockIdx.x;          // b*256 + n
    int b = blk >> 8, n = blk & 255;
    int gy = n >> 4, gx = n & 15;
    int rv = row_of[n];
    int row = (rv >= M1) ? rv : (b * NVIS + rv);
    const float4* src = (const float4*)(dec + (long)row * PE);
    int t = threadIdx.x;           // 0..191, one float4 each
    float4 v = src[t];
    int p  = t * 4;
    int c  = p >> 8, py = (p >> 4) & 15, px = p & 15;
    float4* dst = (float4*)(img + ((long)(b * 3 + c) << 16)
                                + ((gy * 16 + py) << 8) + gx * 16 + px);
    *dst = v;
}

// ---------------------------------------------------------------------------
extern "C" void kernel_launch(void* const* d_in, const int* in_sizes, int n_in,
                              void* d_out, int out_size, void* d_ws, size_t ws_size,
                              hipStream_t stream)
{
    const float* x          = (const float*)d_in[0];
    const float* conv_w     = (const float*)d_in[1];   // (E, 768) row-major
    const float* conv_b     = (const float*)d_in[2];
    const float* pos        = (const float*)d_in[3];   // (N, E)
    const float* mask_token = (const float*)d_in[4];
    const float* W_enc      = (const float*)d_in[5];   // (E, E)
    const float* b_enc      = (const float*)d_in[6];
    const float* W_dec      = (const float*)d_in[7];   // (E, 768)
    const float* b_dec      = (const float*)d_in[8];
    const int*   perm       = (const int*)d_in[9];
    float* out = (float*)d_out;

    float* ws       = (float*)d_ws;
    float* visible  = ws;                                   // M1*EE
    float* full_all = visible + (long)M1 * EE;              // M3*EE
    float* dec_all  = full_all + (long)M3 * EE;             // M3*PE
    int*   row_of   = (int*)(dec_all + (long)M3 * PE);      // 256 ints

    k_gemm1<<<dim3(4, 128), 256, 0, stream>>>(x, conv_w, conv_b, pos, perm, visible);
    k_gemm2<<<dim3(4, 128), 256, 0, stream>>>(visible, W_enc, b_enc, pos, perm, full_all);
    k_maskrows<<<(NMASK * EE + 255) / 256, 256, 0, stream>>>(mask_token, pos, perm, full_all);
    k_gemm3<<<dim3(12, 131), 256, 0, stream>>>(full_all, W_dec, b_dec, dec_all);
    k_prep<<<1, 256, 0, stream>>>(perm, row_of, out + IMG_ELEMS);
    k_fold<<<Bsz * NN, 192, 0, stream>>>(dec_all, row_of, out);
}

// Round 2
// 243.385 us; speedup vs baseline: 1.5997x; 1.5997x over previous
//
#include <hip/hip_runtime.h>

typedef __attribute__((ext_vector_type(8))) __bf16 bf16x8;
typedef __attribute__((ext_vector_type(4))) float f32x4;

constexpr int Bsz   = 128;
constexpr int EE    = 200;
constexpr int EP    = 256;   // padded embed dim
constexpr int KP    = 224;   // padded K loop bound for gemm2/3 (covers 200)
constexpr int NN    = 256;
constexpr int NMASK = 192;
constexpr int NVIS  = 64;
constexpr int PE    = 768;
constexpr int M1    = Bsz * NVIS;   // 8192
constexpr int M3    = M1 + NMASK;   // 8384
constexpr long IMG_ELEMS = (long)Bsz * 3 * 256 * 256;

// ---------------------------------------------------------------------------
// Prep: pad/convert weights to bf16 (B matrices in n-major [n][k] layout),
// pad pos/biases, write masked rows of `full`, emit masked_idx output.
// ---------------------------------------------------------------------------
__global__ __launch_bounds__(256) void k_prep(
    const float* __restrict__ pos, const float* __restrict__ wflat,
    const float* __restrict__ Wenc, const float* __restrict__ Wdec,
    const float* __restrict__ conv_b, const float* __restrict__ b_enc,
    const float* __restrict__ mask_token, const int* __restrict__ perm,
    float* __restrict__ posP, __bf16* __restrict__ W1t,
    __bf16* __restrict__ W2t, __bf16* __restrict__ W3t,
    float* __restrict__ cbp, float* __restrict__ bep,
    __bf16* __restrict__ full, float* __restrict__ out_idx)
{
    int blk = blockIdx.x, t = threadIdx.x;
    if (blk < 256) {                       // posP [256][256]
        posP[blk * 256 + t] = (t < EE) ? pos[blk * EE + t] : 0.f;
        return;
    }
    blk -= 256;
    if (blk < 768) {                       // W1t [256][768] = wflat padded (already n-major)
        int e = blk / 3, k = (blk % 3) * 256 + t;
        W1t[e * 768 + k] = (e < EE) ? (__bf16)wflat[e * 768 + k] : (__bf16)0.f;
        return;
    }
    blk -= 768;
    if (blk < 256) {                       // W2t [256][224] = Wenc^T padded
        if (t < KP) W2t[blk * KP + t] =
            (blk < EE && t < EE) ? (__bf16)Wenc[t * EE + blk] : (__bf16)0.f;
        return;
    }
    blk -= 256;
    if (blk < 768) {                       // W3t [768][224] = Wdec^T padded
        if (t < KP) W3t[blk * KP + t] =
            (t < EE) ? (__bf16)Wdec[t * PE + blk] : (__bf16)0.f;
        return;
    }
    blk -= 768;
    if (blk < NMASK) {                     // masked rows of full: mask_token + pos
        int n = perm[blk];
        full[(M1 + blk) * EP + t] =
            (t < EE) ? (__bf16)(mask_token[t] + pos[n * EE + t]) : (__bf16)0.f;
        return;
    }
    // final block: padded biases + masked_idx output
    cbp[t] = (t < EE) ? conv_b[t] : 0.f;
    bep[t] = (t < EE) ? b_enc[t] : 0.f;
    if (t < NMASK) out_idx[t] = (float)perm[t];
}

// ---------------------------------------------------------------------------
// GEMM1: visible[m][e] = patch(m) . W1t[e] + cb[e] + pos[n][e]   (bf16 MFMA)
// M=8192 K=768 N=256(padded). A gathered from x, converted to bf16.
// ---------------------------------------------------------------------------
__global__ __launch_bounds__(256) void k_gemm1(
    const float* __restrict__ x, const __bf16* __restrict__ W1t,
    const float* __restrict__ cbp, const float* __restrict__ posP,
    const int* __restrict__ perm, __bf16* __restrict__ visible)
{
    __shared__ __bf16 As[64][40];
    __shared__ __bf16 Bs[64][40];
    const int t = threadIdx.x;
    const int m0 = blockIdx.y * 64, e0 = blockIdx.x * 64;
    const int row = t >> 2, chunk = t & 3;
    const int lane = t & 63, wid = t >> 6;
    const int wr = wid >> 1, wc = wid & 1;
    const int quad = lane >> 4, lid = lane & 15;

    // gather base for this thread's A row
    const int am = m0 + row;
    const int an = perm[NMASK + (am & 63)];
    const int abase = (am >> 6) * 196608 + (an >> 4) * 4096 + (an & 15) * 16;

    f32x4 acc[2][2] = {};

    for (int k0 = 0; k0 < PE; k0 += 32) {
        // stage A (gather + convert)
        int k = k0 + chunk * 8;
        int c = k >> 8, py = (k >> 4) & 15, px = k & 15;
        const float* ap = x + abase + c * 65536 + py * 256 + px;
        float4 a0 = *(const float4*)ap;
        float4 a1 = *(const float4*)(ap + 4);
        bf16x8 av;
        av[0] = (__bf16)a0.x; av[1] = (__bf16)a0.y; av[2] = (__bf16)a0.z; av[3] = (__bf16)a0.w;
        av[4] = (__bf16)a1.x; av[5] = (__bf16)a1.y; av[6] = (__bf16)a1.z; av[7] = (__bf16)a1.w;
        *(bf16x8*)&As[row][chunk * 8] = av;
        // stage B (copy bf16)
        *(int4*)&Bs[row][chunk * 8] = *(const int4*)&W1t[(e0 + row) * 768 + k];
        __syncthreads();
        #pragma unroll
        for (int i = 0; i < 2; ++i) {
            bf16x8 af = *(const bf16x8*)&As[wr * 32 + i * 16 + lid][quad * 8];
            #pragma unroll
            for (int j = 0; j < 2; ++j) {
                bf16x8 bfv = *(const bf16x8*)&Bs[wc * 32 + j * 16 + lid][quad * 8];
                acc[i][j] = __builtin_amdgcn_mfma_f32_16x16x32_bf16(af, bfv, acc[i][j], 0, 0, 0);
            }
        }
        __syncthreads();
    }

    #pragma unroll
    for (int i = 0; i < 2; ++i) {
        int mb = m0 + wr * 32 + i * 16 + quad * 4;
        #pragma unroll
        for (int j = 0; j < 2; ++j) {
            int e = e0 + wc * 32 + j * 16 + lid;
            #pragma unroll
            for (int r = 0; r < 4; ++r) {
                int m = mb + r;
                int n = perm[NMASK + (m & 63)];
                float v = acc[i][j][r] + cbp[e] + posP[n * 256 + e];
                visible[m * EP + e] = (__bf16)v;
            }
        }
    }
}

// ---------------------------------------------------------------------------
// GEMM2: full[m][f] = visible[m] . W2t[f] + be[f] + pos[n][f]   (bf16 MFMA)
// M=8192 K=224 N=256.
// ---------------------------------------------------------------------------
__global__ __launch_bounds__(256) void k_gemm2(
    const __bf16* __restrict__ visible, const __bf16* __restrict__ W2t,
    const float* __restrict__ bep, const float* __restrict__ posP,
    const int* __restrict__ perm, __bf16* __restrict__ full)
{
    __shared__ __bf16 As[64][40];
    __shared__ __bf16 Bs[64][40];
    const int t = threadIdx.x;
    const int m0 = blockIdx.y * 64, e0 = blockIdx.x * 64;
    const int row = t >> 2, chunk = t & 3;
    const int lane = t & 63, wid = t >> 6;
    const int wr = wid >> 1, wc = wid & 1;
    const int quad = lane >> 4, lid = lane & 15;

    f32x4 acc[2][2] = {};

    for (int k0 = 0; k0 < KP; k0 += 32) {
        int k = k0 + chunk * 8;
        *(int4*)&As[row][chunk * 8] = *(const int4*)&visible[(m0 + row) * EP + k];
        *(int4*)&Bs[row][chunk * 8] = *(const int4*)&W2t[(e0 + row) * KP + k];
        __syncthreads();
        #pragma unroll
        for (int i = 0; i < 2; ++i) {
            bf16x8 af = *(const bf16x8*)&As[wr * 32 + i * 16 + lid][quad * 8];
            #pragma unroll
            for (int j = 0; j < 2; ++j) {
                bf16x8 bfv = *(const bf16x8*)&Bs[wc * 32 + j * 16 + lid][quad * 8];
                acc[i][j] = __builtin_amdgcn_mfma_f32_16x16x32_bf16(af, bfv, acc[i][j], 0, 0, 0);
            }
        }
        __syncthreads();
    }

    #pragma unroll
    for (int i = 0; i < 2; ++i) {
        int mb = m0 + wr * 32 + i * 16 + quad * 4;
        #pragma unroll
        for (int j = 0; j < 2; ++j) {
            int e = e0 + wc * 32 + j * 16 + lid;
            #pragma unroll
            for (int r = 0; r < 4; ++r) {
                int m = mb + r;
                int n = perm[NMASK + (m & 63)];
                float v = acc[i][j][r] + bep[e] + posP[n * 256 + e];
                full[m * EP + e] = (__bf16)v;
            }
        }
    }
}

// ---------------------------------------------------------------------------
// GEMM3: dec[m][p] = full[m] . W3t[p] + bd[p].  M=8384 K=224 N=768.
// Visible rows (m<8192) write straight into the output image; masked rows
// (batch-independent) go to dec_masked for the broadcast kernel.
// ---------------------------------------------------------------------------
__global__ __launch_bounds__(256) void k_gemm3(
    const __bf16* __restrict__ full, const __bf16* __restrict__ W3t,
    const float* __restrict__ bdec, const int* __restrict__ perm,
    float* __restrict__ img, float* __restrict__ dec_masked)
{
    __shared__ __bf16 As[64][40];
    __shared__ __bf16 Bs[64][40];
    const int t = threadIdx.x;
    const int m0 = blockIdx.y * 64, e0 = blockIdx.x * 64;
    const int row = t >> 2, chunk = t & 3;
    const int lane = t & 63, wid = t >> 6;
    const int wr = wid >> 1, wc = wid & 1;
    const int quad = lane >> 4, lid = lane & 15;

    f32x4 acc[2][2] = {};

    for (int k0 = 0; k0 < KP; k0 += 32) {
        int k = k0 + chunk * 8;
        *(int4*)&As[row][chunk * 8] = *(const int4*)&full[(m0 + row) * EP + k];
        *(int4*)&Bs[row][chunk * 8] = *(const int4*)&W3t[(e0 + row) * KP + k];
        __syncthreads();
        #pragma unroll
        for (int i = 0; i < 2; ++i) {
            bf16x8 af = *(const bf16x8*)&As[wr * 32 + i * 16 + lid][quad * 8];
            #pragma unroll
            for (int j = 0; j < 2; ++j) {
                bf16x8 bfv = *(const bf16x8*)&Bs[wc * 32 + j * 16 + lid][quad * 8];
                acc[i][j] = __builtin_amdgcn_mfma_f32_16x16x32_bf16(af, bfv, acc[i][j], 0, 0, 0);
            }
        }
        __syncthreads();
    }

    const bool vis = (m0 < M1);
    #pragma unroll
    for (int i = 0; i < 2; ++i) {
        int mb = m0 + wr * 32 + i * 16 + quad * 4;
        #pragma unroll
        for (int j = 0; j < 2; ++j) {
            int e = e0 + wc * 32 + j * 16 + lid;
            int c = e >> 8, py = (e >> 4) & 15, px = e & 15;
            #pragma unroll
            for (int r = 0; r < 4; ++r) {
                int m = mb + r;
                float v = acc[i][j][r] + bdec[e];
                if (vis) {
                    int b = m >> 6;
                    int n = perm[NMASK + (m & 63)];
                    img[(long)(b * 3 + c) * 65536 + ((n >> 4) * 16 + py) * 256
                        + (n & 15) * 16 + px] = v;
                } else {
                    dec_masked[(m - M1) * PE + e] = v;
                }
            }
        }
    }
}

// ---------------------------------------------------------------------------
// Broadcast masked decoder rows (batch-independent) to all images.
// ---------------------------------------------------------------------------
__global__ __launch_bounds__(192) void k_foldmask(
    const float* __restrict__ dec_masked, const int* __restrict__ perm,
    float* __restrict__ img)
{
    const int i = blockIdx.x;      // masked patch slot 0..191
    const int b = blockIdx.y;      // batch
    const int n = perm[i];
    const int t = threadIdx.x;
    float4 v = *(const float4*)&dec_masked[i * PE + t * 4];
    int p = t * 4;
    int c = p >> 8, py = (p >> 4) & 15, px = p & 15;
    *(float4*)&img[(long)(b * 3 + c) * 65536 + ((n >> 4) * 16 + py) * 256
                   + (n & 15) * 16 + px] = v;
}

// ---------------------------------------------------------------------------
extern "C" void kernel_launch(void* const* d_in, const int* in_sizes, int n_in,
                              void* d_out, int out_size, void* d_ws, size_t ws_size,
                              hipStream_t stream)
{
    const float* x          = (const float*)d_in[0];
    const float* conv_w     = (const float*)d_in[1];
    const float* conv_b     = (const float*)d_in[2];
    const float* pos        = (const float*)d_in[3];
    const float* mask_token = (const float*)d_in[4];
    const float* W_enc      = (const float*)d_in[5];
    const float* b_enc      = (const float*)d_in[6];
    const float* W_dec      = (const float*)d_in[7];
    const float* b_dec      = (const float*)d_in[8];
    const int*   perm       = (const int*)d_in[9];
    float* out = (float*)d_out;

    // workspace carve-up (all offsets 16B-aligned)
    __bf16* visible = (__bf16*)d_ws;                    // 8192*256
    __bf16* full    = visible + M1 * EP;                // 8384*256
    __bf16* W1t     = full + M3 * EP;                   // 256*768
    __bf16* W2t     = W1t + 256 * 768;                  // 256*224
    __bf16* W3t     = W2t + 256 * KP;                   // 768*224
    float*  posP    = (float*)(W3t + 768 * KP);         // 256*256
    float*  cbp     = posP + 256 * 256;                 // 256
    float*  bep     = cbp + 256;                        // 256
    float*  decm    = bep + 256;                        // 192*768

    k_prep<<<256 + 768 + 256 + 768 + NMASK + 1, 256, 0, stream>>>(
        pos, conv_w, W_enc, W_dec, conv_b, b_enc, mask_token, perm,
        posP, W1t, W2t, W3t, cbp, bep, full, out + IMG_ELEMS);
    k_gemm1<<<dim3(4, 128), 256, 0, stream>>>(x, W1t, cbp, posP, perm, visible);
    k_gemm2<<<dim3(4, 128), 256, 0, stream>>>(visible, W2t, bep, posP, perm, full);
    k_gemm3<<<dim3(12, 131), 256, 0, stream>>>(full, W3t, b_dec, perm, out, decm);
    k_foldmask<<<dim3(NMASK, Bsz), 192, 0, stream>>>(decm, perm, out);
}